// Round 1
// baseline (1161.749 us; speedup 1.0000x reference)
//
#include <hip/hip_runtime.h>

#define T_STEPS 2048
#define BATCH   2
#define IDIM    40
#define HDIM    44
#define GDIM    176      // 4*H
#define ADIM    262144
#define EDIM    88       // 2*H

__device__ __forceinline__ float fast_sigmoid(float x) {
    return 1.0f / (1.0f + __expf(-x));
}
__device__ __forceinline__ float fast_tanh(float x) {
    // exact identity: tanh(x) = 1 - 2/(exp(2x)+1); saturates correctly at +/-inf
    return 1.0f - 2.0f / (__expf(2.0f * x) + 1.0f);
}

// K1: xproj[t][b][gi] = b_ih[gi] + b_hh[gi] + sum_i x[t][b][i] * W_ih[gi][i]
__global__ __launch_bounds__(192) void xproj_kernel(
    const float* __restrict__ x,      // [T][B][40]
    const float* __restrict__ W_ih,   // [176][40]
    const float* __restrict__ b_ih,   // [176]
    const float* __restrict__ b_hh,   // [176]
    float* __restrict__ xproj)        // [T][B][176]
{
    const int tb = blockIdx.x;        // t*B + b
    const int gi = threadIdx.x;
    __shared__ __align__(16) float xs[IDIM];
    if (threadIdx.x < IDIM) xs[threadIdx.x] = x[(size_t)tb * IDIM + threadIdx.x];
    __syncthreads();
    if (gi < GDIM) {
        const float* wr = W_ih + gi * IDIM;
        float a0 = 0.f, a1 = 0.f;
        #pragma unroll
        for (int i = 0; i < IDIM; i += 4) {
            float4 wv = *(const float4*)&wr[i];
            float4 xv = *(const float4*)&xs[i];
            a0 += wv.x * xv.x + wv.z * xv.z;
            a1 += wv.y * xv.y + wv.w * xv.w;
        }
        xproj[(size_t)tb * GDIM + gi] = a0 + a1 + b_ih[gi] + b_hh[gi];
    }
}

// K2: serial LSTM over T steps; one block per batch. Produces base[b] = emb.w_e + b_v
__global__ __launch_bounds__(192) void lstm_kernel(
    const float* __restrict__ xproj,  // [T][B][176]
    const float* __restrict__ h0,     // [1][B][44]
    const float* __restrict__ c0,     // [1][B][44]
    const float* __restrict__ W_hh,   // [176][44]
    const float* __restrict__ W_v,    // [1][128]
    const float* __restrict__ b_v,    // [1]
    float* __restrict__ base_out)     // [B]
{
    const int b = blockIdx.x;
    const int t = threadIdx.x;        // 0..191

    __shared__ __align__(16) float h_sh[HDIM];
    __shared__ __align__(16) float c_sh[HDIM];
    __shared__ __align__(16) float g_sh[GDIM];

    // per-thread W_hh row in registers
    float w[HDIM];
    if (t < GDIM) {
        const float* wr = W_hh + t * HDIM;
        #pragma unroll
        for (int k = 0; k < HDIM; ++k) w[k] = wr[k];
    }
    if (t < HDIM) h_sh[t] = h0[b * HDIM + t];
    float c = (t < HDIM) ? c0[b * HDIM + t] : 0.f;
    __syncthreads();

    const float* xp = xproj + (size_t)b * GDIM;   // step stride = B*GDIM
    float xnext = (t < GDIM) ? xp[t] : 0.f;

    for (int step = 0; step < T_STEPS; ++step) {
        float xcur = xnext;
        if (step + 1 < T_STEPS && t < GDIM)
            xnext = xp[(size_t)(step + 1) * (BATCH * GDIM) + t];

        if (t < GDIM) {
            float a0 = 0.f, a1 = 0.f, a2 = 0.f, a3 = 0.f;
            #pragma unroll
            for (int k = 0; k < HDIM; k += 4) {
                float4 hv = *(const float4*)&h_sh[k];   // broadcast read
                a0 += w[k + 0] * hv.x;
                a1 += w[k + 1] * hv.y;
                a2 += w[k + 2] * hv.z;
                a3 += w[k + 3] * hv.w;
            }
            g_sh[t] = xcur + ((a0 + a1) + (a2 + a3));
        }
        __syncthreads();

        if (t < HDIM) {
            float gi = g_sh[t];
            float gf = g_sh[HDIM + t];
            float gg = g_sh[2 * HDIM + t];
            float go = g_sh[3 * HDIM + t];
            float si = fast_sigmoid(gi);
            float sf = fast_sigmoid(gf);
            float so = fast_sigmoid(go);
            float tg = fast_tanh(gg);
            c = sf * c + si * tg;
            h_sh[t] = so * fast_tanh(c);
        }
        __syncthreads();
    }

    if (t < HDIM) c_sh[t] = c;
    __syncthreads();
    if (t == 0) {
        float base = b_v[0];
        for (int j = 0; j < HDIM; ++j)
            base += h_sh[j] * W_v[j] + c_sh[j] * W_v[HDIM + j];
        base_out[b] = base;
    }
}

// K3: out[b][a] = (a < len[b]) ? base[b] + action[b][a][:].w_a : 0
__global__ __launch_bounds__(256) void action_kernel(
    const float* __restrict__ action,     // [B][A][40]
    const int*   __restrict__ act_length, // [B]
    const float* __restrict__ W_v,        // [1][128]; w_a = W_v[88..127]
    const float* __restrict__ base,       // [B]
    float* __restrict__ out)              // [B][A]
{
    const int idx = blockIdx.x * 256 + threadIdx.x;   // 0 .. B*A-1
    const int b = idx >> 18;                          // A = 2^18
    const int a = idx & (ADIM - 1);
    if (a >= act_length[b]) { out[idx] = 0.f; return; }
    const float* row = action + (size_t)idx * IDIM;
    float a0 = 0.f, a1 = 0.f;
    #pragma unroll
    for (int i = 0; i < IDIM; i += 4) {
        float4 av = *(const float4*)&row[i];
        a0 += av.x * W_v[EDIM + i + 0] + av.z * W_v[EDIM + i + 2];
        a1 += av.y * W_v[EDIM + i + 1] + av.w * W_v[EDIM + i + 3];
    }
    out[idx] = base[b] + a0 + a1;
}

extern "C" void kernel_launch(void* const* d_in, const int* in_sizes, int n_in,
                              void* d_out, int out_size, void* d_ws, size_t ws_size,
                              hipStream_t stream) {
    const float* x        = (const float*)d_in[0];
    const float* h0       = (const float*)d_in[1];
    const float* c0       = (const float*)d_in[2];
    const float* action   = (const float*)d_in[3];
    const int*   act_len  = (const int*)  d_in[4];
    const float* W_ih     = (const float*)d_in[5];
    const float* W_hh     = (const float*)d_in[6];
    const float* b_ih     = (const float*)d_in[7];
    const float* b_hh     = (const float*)d_in[8];
    const float* W_v      = (const float*)d_in[9];
    const float* b_v      = (const float*)d_in[10];
    float* out = (float*)d_out;

    float* xproj = (float*)d_ws;                                   // T*B*176 floats
    float* base  = xproj + (size_t)T_STEPS * BATCH * GDIM;         // B floats

    xproj_kernel<<<dim3(T_STEPS * BATCH), dim3(192), 0, stream>>>(
        x, W_ih, b_ih, b_hh, xproj);
    lstm_kernel<<<dim3(BATCH), dim3(192), 0, stream>>>(
        xproj, h0, c0, W_hh, W_v, b_v, base);
    action_kernel<<<dim3((BATCH * ADIM) / 256), dim3(256), 0, stream>>>(
        action, act_len, W_v, base, out);
}

// Round 2
// 777.663 us; speedup vs baseline: 1.4939x; 1.4939x over previous
//
#include <hip/hip_runtime.h>

typedef float v2f __attribute__((ext_vector_type(2)));
typedef float v4f __attribute__((ext_vector_type(4)));

#define T_STEPS 2048
#define BATCH   2
#define IDIM    40
#define HDIM    44
#define GDIM    176      // 4*H
#define ADIM    262144
#define EDIM    88       // 2*H

__device__ __forceinline__ float fast_sigmoid(float x) {
    return __builtin_amdgcn_rcpf(1.0f + __expf(-x));
}
__device__ __forceinline__ float fast_tanh(float x) {
    // tanh(x) = 1 - 2/(exp(2x)+1); saturates correctly
    return 1.0f - 2.0f * __builtin_amdgcn_rcpf(__expf(2.0f * x) + 1.0f);
}
__device__ __forceinline__ void pk_fma(v2f& acc, v2f a, v2f b) {
    asm("v_pk_fma_f32 %0, %1, %2, %0" : "+v"(acc) : "v"(a), "v"(b));
}

// K1: xproj[t][b][gi] = b_ih[gi] + b_hh[gi] + sum_i x[t][b][i] * W_ih[gi][i]
__global__ __launch_bounds__(192) void xproj_kernel(
    const float* __restrict__ x,      // [T][B][40]
    const float* __restrict__ W_ih,   // [176][40]
    const float* __restrict__ b_ih,   // [176]
    const float* __restrict__ b_hh,   // [176]
    float* __restrict__ xproj)        // [T][B][176]
{
    const int tb = blockIdx.x;        // t*B + b
    const int gi = threadIdx.x;
    __shared__ __align__(16) float xs[IDIM];
    if (threadIdx.x < IDIM) xs[threadIdx.x] = x[(size_t)tb * IDIM + threadIdx.x];
    __syncthreads();
    if (gi < GDIM) {
        const float* wr = W_ih + gi * IDIM;
        float a0 = 0.f, a1 = 0.f;
        #pragma unroll
        for (int i = 0; i < IDIM; i += 4) {
            float4 wv = *(const float4*)&wr[i];
            float4 xv = *(const float4*)&xs[i];
            a0 += wv.x * xv.x + wv.z * xv.z;
            a1 += wv.y * xv.y + wv.w * xv.w;
        }
        xproj[(size_t)tb * GDIM + gi] = a0 + a1 + b_ih[gi] + b_hh[gi];
    }
}

// K2: serial LSTM, ONE WAVE per batch. Lane j owns h[j], c[j] and gate rows
// {j, 44+j, 88+j, 132+j} of W_hh in registers. h broadcast via LDS.
__global__ __launch_bounds__(64, 1) void lstm_kernel(
    const float* __restrict__ xproj,  // [T][B][176]
    const float* __restrict__ h0,     // [1][B][44]
    const float* __restrict__ c0,     // [1][B][44]
    const float* __restrict__ W_hh,   // [176][44]
    const float* __restrict__ W_v,    // [1][128]
    const float* __restrict__ b_v,    // [1]
    float* __restrict__ base_out)     // [B]
{
    const int b = blockIdx.x;
    const int j = threadIdx.x;        // 0..63; lanes >= 44 are passengers

    __shared__ __align__(16) float h_sh[HDIM];

    // Per-lane weight rows in registers (4 x 44 = 176 VGPRs as 88 v2f pairs)
    v2f wi[22], wf[22], wg[22], wo[22];
    if (j < HDIM) {
        const float* ri = W_hh + (size_t)j * HDIM;
        const float* rf = W_hh + (size_t)(HDIM + j) * HDIM;
        const float* rg = W_hh + (size_t)(2 * HDIM + j) * HDIM;
        const float* ro = W_hh + (size_t)(3 * HDIM + j) * HDIM;
        #pragma unroll
        for (int k = 0; k < 22; ++k) {
            wi[k] = ((const v2f*)ri)[k];
            wf[k] = ((const v2f*)rf)[k];
            wg[k] = ((const v2f*)rg)[k];
            wo[k] = ((const v2f*)ro)[k];
        }
    } else {
        #pragma unroll
        for (int k = 0; k < 22; ++k) {
            wi[k] = (v2f)(0.f); wf[k] = (v2f)(0.f);
            wg[k] = (v2f)(0.f); wo[k] = (v2f)(0.f);
        }
    }

    float c = 0.f, hval = 0.f;
    if (j < HDIM) {
        c = c0[b * HDIM + j];
        h_sh[j] = h0[b * HDIM + j];
    }
    __syncthreads();

    // broadcast-read full h into registers (all lanes)
    v2f hp[22];
    #pragma unroll
    for (int k = 0; k < 11; ++k) {
        v4f t = ((const v4f*)h_sh)[k];
        hp[2 * k]     = __builtin_shufflevector(t, t, 0, 1);
        hp[2 * k + 1] = __builtin_shufflevector(t, t, 2, 3);
    }

    const float* xp = xproj + (size_t)b * GDIM;   // step stride = B*GDIM
    float xc0 = xp[j], xc1 = xp[HDIM + j], xc2 = xp[2 * HDIM + j], xc3 = xp[3 * HDIM + j];

    #pragma unroll 1
    for (int step = 0; step < T_STEPS; ++step) {
        // prefetch next step's xproj (L2-resident, hidden under FMAs)
        const int nstep = (step + 1 < T_STEPS) ? step + 1 : step;
        const float* xn = xp + (size_t)nstep * (BATCH * GDIM);
        float xn0 = xn[j], xn1 = xn[HDIM + j], xn2 = xn[2 * HDIM + j], xn3 = xn[3 * HDIM + j];

        // 4 gate dot-products, 2 packed accumulators each (8 indep chains)
        v2f ai0 = (v2f)(0.f), ai1 = (v2f)(0.f);
        v2f af0 = (v2f)(0.f), af1 = (v2f)(0.f);
        v2f ag0 = (v2f)(0.f), ag1 = (v2f)(0.f);
        v2f ao0 = (v2f)(0.f), ao1 = (v2f)(0.f);
        #pragma unroll
        for (int k = 0; k < 22; k += 2) {
            pk_fma(ai0, wi[k], hp[k]); pk_fma(ai1, wi[k + 1], hp[k + 1]);
            pk_fma(af0, wf[k], hp[k]); pk_fma(af1, wf[k + 1], hp[k + 1]);
            pk_fma(ag0, wg[k], hp[k]); pk_fma(ag1, wg[k + 1], hp[k + 1]);
            pk_fma(ao0, wo[k], hp[k]); pk_fma(ao1, wo[k + 1], hp[k + 1]);
        }
        v2f si2 = ai0 + ai1; float gi = si2.x + si2.y + xc0;
        v2f sf2 = af0 + af1; float gf = sf2.x + sf2.y + xc1;
        v2f sg2 = ag0 + ag1; float gg = sg2.x + sg2.y + xc2;
        v2f so2 = ao0 + ao1; float go = so2.x + so2.y + xc3;

        float s_i = fast_sigmoid(gi);
        float s_f = fast_sigmoid(gf);
        float s_o = fast_sigmoid(go);
        float t_g = fast_tanh(gg);
        c = s_f * c + s_i * t_g;
        hval = s_o * fast_tanh(c);

        if (j < HDIM) h_sh[j] = hval;
        __syncthreads();   // single wave: compiles to lgkmcnt wait, no hw barrier cost

        #pragma unroll
        for (int k = 0; k < 11; ++k) {
            v4f t = ((const v4f*)h_sh)[k];
            hp[2 * k]     = __builtin_shufflevector(t, t, 0, 1);
            hp[2 * k + 1] = __builtin_shufflevector(t, t, 2, 3);
        }
        xc0 = xn0; xc1 = xn1; xc2 = xn2; xc3 = xn3;
    }

    // epilogue: base[b] = sum_j h[j]*Wv[j] + c[j]*Wv[44+j] + b_v
    float p = 0.f;
    if (j < HDIM) p = hval * W_v[j] + c * W_v[HDIM + j];
    #pragma unroll
    for (int off = 32; off; off >>= 1) p += __shfl_down(p, off);
    if (j == 0) base_out[b] = p + b_v[0];
}

// K3: out[b][a] = (a < len[b]) ? base[b] + action[b][a][:].w_a : 0
__global__ __launch_bounds__(256) void action_kernel(
    const float* __restrict__ action,     // [B][A][40]
    const int*   __restrict__ act_length, // [B]
    const float* __restrict__ W_v,        // [1][128]; w_a = W_v[88..127]
    const float* __restrict__ base,       // [B]
    float* __restrict__ out)              // [B][A]
{
    const int idx = blockIdx.x * 256 + threadIdx.x;   // 0 .. B*A-1
    const int b = idx >> 18;                          // A = 2^18
    const int a = idx & (ADIM - 1);
    if (a >= act_length[b]) { out[idx] = 0.f; return; }
    const float* row = action + (size_t)idx * IDIM;
    float a0 = 0.f, a1 = 0.f;
    #pragma unroll
    for (int i = 0; i < IDIM; i += 4) {
        float4 av = *(const float4*)&row[i];
        a0 += av.x * W_v[EDIM + i + 0] + av.z * W_v[EDIM + i + 2];
        a1 += av.y * W_v[EDIM + i + 1] + av.w * W_v[EDIM + i + 3];
    }
    out[idx] = base[b] + a0 + a1;
}

extern "C" void kernel_launch(void* const* d_in, const int* in_sizes, int n_in,
                              void* d_out, int out_size, void* d_ws, size_t ws_size,
                              hipStream_t stream) {
    const float* x        = (const float*)d_in[0];
    const float* h0       = (const float*)d_in[1];
    const float* c0       = (const float*)d_in[2];
    const float* action   = (const float*)d_in[3];
    const int*   act_len  = (const int*)  d_in[4];
    const float* W_ih     = (const float*)d_in[5];
    const float* W_hh     = (const float*)d_in[6];
    const float* b_ih     = (const float*)d_in[7];
    const float* b_hh     = (const float*)d_in[8];
    const float* W_v      = (const float*)d_in[9];
    const float* b_v      = (const float*)d_in[10];
    float* out = (float*)d_out;

    float* xproj = (float*)d_ws;                                   // T*B*176 floats
    float* base  = xproj + (size_t)T_STEPS * BATCH * GDIM;         // B floats

    xproj_kernel<<<dim3(T_STEPS * BATCH), dim3(192), 0, stream>>>(
        x, W_ih, b_ih, b_hh, xproj);
    lstm_kernel<<<dim3(BATCH), dim3(64), 0, stream>>>(
        xproj, h0, c0, W_hh, W_v, b_v, base);
    action_kernel<<<dim3((BATCH * ADIM) / 256), dim3(256), 0, stream>>>(
        action, act_len, W_v, base, out);
}

// Round 3
// 756.614 us; speedup vs baseline: 1.5355x; 1.0278x over previous
//
#include <hip/hip_runtime.h>

typedef float v2f __attribute__((ext_vector_type(2)));
typedef float v4f __attribute__((ext_vector_type(4)));

#define T_STEPS 2048
#define BATCH   2
#define IDIM    40
#define HDIM    44
#define GDIM    176      // 4*H
#define ADIM    262144
#define EDIM    88       // 2*H

__device__ __forceinline__ float fast_sigmoid(float x) {
    return __builtin_amdgcn_rcpf(1.0f + __expf(-x));
}
__device__ __forceinline__ float fast_tanh(float x) {
    // tanh(x) = 1 - 2/(exp(2x)+1); saturates correctly
    return 1.0f - 2.0f * __builtin_amdgcn_rcpf(__expf(2.0f * x) + 1.0f);
}
__device__ __forceinline__ void pk_fma(v2f& acc, v2f a, v2f b) {
    asm("v_pk_fma_f32 %0, %1, %2, %0" : "+v"(acc) : "v"(a), "v"(b));
}

// K1: xproj[t][b][gi] = b_ih[gi] + b_hh[gi] + sum_i x[t][b][i] * W_ih[gi][i]
__global__ __launch_bounds__(192) void xproj_kernel(
    const float* __restrict__ x,      // [T][B][40]
    const float* __restrict__ W_ih,   // [176][40]
    const float* __restrict__ b_ih,   // [176]
    const float* __restrict__ b_hh,   // [176]
    float* __restrict__ xproj)        // [T][B][176]
{
    const int tb = blockIdx.x;        // t*B + b
    const int gi = threadIdx.x;
    __shared__ __align__(16) float xs[IDIM];
    if (threadIdx.x < IDIM) xs[threadIdx.x] = x[(size_t)tb * IDIM + threadIdx.x];
    __syncthreads();
    if (gi < GDIM) {
        const float* wr = W_ih + gi * IDIM;
        float a0 = 0.f, a1 = 0.f;
        #pragma unroll
        for (int i = 0; i < IDIM; i += 4) {
            float4 wv = *(const float4*)&wr[i];
            float4 xv = *(const float4*)&xs[i];
            a0 += wv.x * xv.x + wv.z * xv.z;
            a1 += wv.y * xv.y + wv.w * xv.w;
        }
        xproj[(size_t)tb * GDIM + gi] = a0 + a1 + b_ih[gi] + b_hh[gi];
    }
}

// K2: serial LSTM, ONE WAVE per batch. Lane j owns h[j], c[j] and gate rows
// {j, 44+j, 88+j, 132+j} of W_hh in registers (176 VGPRs). h broadcast via LDS.
// Register budget kept < 256 arch VGPRs so nothing lands in AGPRs.
__global__ __launch_bounds__(64, 1) void lstm_kernel(
    const float* __restrict__ xproj,  // [T][B][176]
    const float* __restrict__ h0,     // [1][B][44]
    const float* __restrict__ c0,     // [1][B][44]
    const float* __restrict__ W_hh,   // [176][44]
    const float* __restrict__ W_v,    // [1][128]
    const float* __restrict__ b_v,    // [1]
    float* __restrict__ base_out)     // [B]
{
    const int b = blockIdx.x;
    const int j = threadIdx.x;          // 0..63; lanes >= 44 are passengers
    const int jj = (j < HDIM) ? j : (HDIM - 1);   // clamped for loads (no OOB)

    __shared__ __align__(16) float h_sh[HDIM];

    // Per-lane weight rows in registers (4 x 44 = 176 VGPRs as 88 v2f pairs)
    v2f wi[22], wf[22], wg[22], wo[22];
    {
        const float* ri = W_hh + (size_t)jj * HDIM;
        const float* rf = W_hh + (size_t)(HDIM + jj) * HDIM;
        const float* rg = W_hh + (size_t)(2 * HDIM + jj) * HDIM;
        const float* ro = W_hh + (size_t)(3 * HDIM + jj) * HDIM;
        #pragma unroll
        for (int k = 0; k < 22; ++k) {
            wi[k] = ((const v2f*)ri)[k];
            wf[k] = ((const v2f*)rf)[k];
            wg[k] = ((const v2f*)rg)[k];
            wo[k] = ((const v2f*)ro)[k];
        }
    }

    float c = c0[b * HDIM + jj];
    if (j < HDIM) h_sh[j] = h0[b * HDIM + j];
    __syncthreads();

    // broadcast-read full h into registers (all lanes)
    v2f hp[22];
    #pragma unroll
    for (int k = 0; k < 11; ++k) {
        v4f t = ((const v4f*)h_sh)[k];
        hp[2 * k]     = __builtin_shufflevector(t, t, 0, 1);
        hp[2 * k + 1] = __builtin_shufflevector(t, t, 2, 3);
    }

    const float* xp = xproj + (size_t)b * GDIM;   // step stride = B*GDIM
    float xc0 = xp[jj], xc1 = xp[HDIM + jj], xc2 = xp[2 * HDIM + jj], xc3 = xp[3 * HDIM + jj];
    float hval = 0.f;

    #pragma unroll 1
    for (int step = 0; step < T_STEPS; ++step) {
        // prefetch next step's xproj (L2-resident, hidden under FMAs)
        const int nstep = (step + 1 < T_STEPS) ? step + 1 : step;
        const float* xn = xp + (size_t)nstep * (BATCH * GDIM);
        float xn0 = xn[jj], xn1 = xn[HDIM + jj], xn2 = xn[2 * HDIM + jj], xn3 = xn[3 * HDIM + jj];

        // 4 gate dot-products, one packed accumulator chain per gate
        v2f ai = (v2f)(0.f), af = (v2f)(0.f), ag = (v2f)(0.f), ao = (v2f)(0.f);
        #pragma unroll
        for (int k = 0; k < 22; ++k) {
            pk_fma(ai, wi[k], hp[k]);
            pk_fma(af, wf[k], hp[k]);
            pk_fma(ag, wg[k], hp[k]);
            pk_fma(ao, wo[k], hp[k]);
        }
        float gi = ai.x + ai.y + xc0;
        float gf = af.x + af.y + xc1;
        float gg = ag.x + ag.y + xc2;
        float go = ao.x + ao.y + xc3;

        float s_i = fast_sigmoid(gi);
        float s_f = fast_sigmoid(gf);
        float s_o = fast_sigmoid(go);
        float t_g = fast_tanh(gg);
        c = s_f * c + s_i * t_g;
        hval = s_o * fast_tanh(c);

        if (j < HDIM) h_sh[j] = hval;
        __syncthreads();

        #pragma unroll
        for (int k = 0; k < 11; ++k) {
            v4f t = ((const v4f*)h_sh)[k];
            hp[2 * k]     = __builtin_shufflevector(t, t, 0, 1);
            hp[2 * k + 1] = __builtin_shufflevector(t, t, 2, 3);
        }
        xc0 = xn0; xc1 = xn1; xc2 = xn2; xc3 = xn3;
    }

    // epilogue: base[b] = sum_j h[j]*Wv[j] + c[j]*Wv[44+j] + b_v
    float p = 0.f;
    if (j < HDIM) p = hval * W_v[j] + c * W_v[HDIM + j];
    #pragma unroll
    for (int off = 32; off; off >>= 1) p += __shfl_down(p, off);
    if (j == 0) base_out[b] = p + b_v[0];
}

// K3: out[b][a] = (a < len[b]) ? base[b] + action[b][a][:].w_a : 0
__global__ __launch_bounds__(256) void action_kernel(
    const float* __restrict__ action,     // [B][A][40]
    const int*   __restrict__ act_length, // [B]
    const float* __restrict__ W_v,        // [1][128]; w_a = W_v[88..127]
    const float* __restrict__ base,       // [B]
    float* __restrict__ out)              // [B][A]
{
    const int idx = blockIdx.x * 256 + threadIdx.x;   // 0 .. B*A-1
    const int b = idx >> 18;                          // A = 2^18
    const int a = idx & (ADIM - 1);
    if (a >= act_length[b]) { out[idx] = 0.f; return; }
    const float* row = action + (size_t)idx * IDIM;
    float a0 = 0.f, a1 = 0.f;
    #pragma unroll
    for (int i = 0; i < IDIM; i += 4) {
        float4 av = *(const float4*)&row[i];
        a0 += av.x * W_v[EDIM + i + 0] + av.z * W_v[EDIM + i + 2];
        a1 += av.y * W_v[EDIM + i + 1] + av.w * W_v[EDIM + i + 3];
    }
    out[idx] = base[b] + a0 + a1;
}

extern "C" void kernel_launch(void* const* d_in, const int* in_sizes, int n_in,
                              void* d_out, int out_size, void* d_ws, size_t ws_size,
                              hipStream_t stream) {
    const float* x        = (const float*)d_in[0];
    const float* h0       = (const float*)d_in[1];
    const float* c0       = (const float*)d_in[2];
    const float* action   = (const float*)d_in[3];
    const int*   act_len  = (const int*)  d_in[4];
    const float* W_ih     = (const float*)d_in[5];
    const float* W_hh     = (const float*)d_in[6];
    const float* b_ih     = (const float*)d_in[7];
    const float* b_hh     = (const float*)d_in[8];
    const float* W_v      = (const float*)d_in[9];
    const float* b_v      = (const float*)d_in[10];
    float* out = (float*)d_out;

    float* xproj = (float*)d_ws;                                   // T*B*176 floats
    float* base  = xproj + (size_t)T_STEPS * BATCH * GDIM;         // B floats

    xproj_kernel<<<dim3(T_STEPS * BATCH), dim3(192), 0, stream>>>(
        x, W_ih, b_ih, b_hh, xproj);
    lstm_kernel<<<dim3(BATCH), dim3(64), 0, stream>>>(
        xproj, h0, c0, W_hh, W_v, b_v, base);
    action_kernel<<<dim3((BATCH * ADIM) / 256), dim3(256), 0, stream>>>(
        action, act_len, W_v, base, out);
}